// Round 6
// baseline (245.277 us; speedup 1.0000x reference)
//
#include <hip/hip_runtime.h>
#include <math.h>

#define B_  8
#define N_  2048
#define F_  128
#define H1_ 32
#define H2_ 64
#define D1_ 128
#define KS_ 4            // K-split factor for the A-GEMMs
#define KSEG_ (N_ / KS_) // 512 K per block

typedef unsigned short u16;
typedef unsigned int   u32;
typedef __attribute__((ext_vector_type(8))) short short8;  // 8 bf16 (4 VGPRs)
typedef __attribute__((ext_vector_type(4))) float f32x4;

// ---------------- kernel 1: xw1 = x @ W1   [B*N,128] @ [128,32] ----------------
__global__ __launch_bounds__(256) void k_xw1(const float* __restrict__ x,
                                             const float* __restrict__ W1,
                                             float* __restrict__ xw1) {
  __shared__ float w_s[F_ * H1_];
  for (int i = threadIdx.x; i < F_ * H1_; i += 256) w_s[i] = W1[i];
  __syncthreads();
  int idx = blockIdx.x * 256 + threadIdx.x;     // over B*N*H1
  int row = idx >> 5, col = idx & 31;
  const float* xr = x + (size_t)row * F_;
  float acc = 0.f;
#pragma unroll
  for (int k = 0; k < F_; k += 4) {
    float4 xv = *(const float4*)(xr + k);
    acc = fmaf(xv.x, w_s[(k + 0) * H1_ + col], acc);
    acc = fmaf(xv.y, w_s[(k + 1) * H1_ + col], acc);
    acc = fmaf(xv.z, w_s[(k + 2) * H1_ + col], acc);
    acc = fmaf(xv.w, w_s[(k + 3) * H1_ + col], acc);
  }
  xw1[idx] = acc;
}

// ---------------- kernel: hw2 = h1 @ W2   [B*N,32] @ [32,64] ----------------
__global__ __launch_bounds__(256) void k_hw2(const float* __restrict__ h1,
                                             const float* __restrict__ W2,
                                             float* __restrict__ hw2) {
  __shared__ float w_s[H1_ * H2_];
  for (int i = threadIdx.x; i < H1_ * H2_; i += 256) w_s[i] = W2[i];
  __syncthreads();
  int idx = blockIdx.x * 256 + threadIdx.x;     // over B*N*H2
  int row = idx >> 6, col = idx & 63;
  const float* hr = h1 + (size_t)row * H1_;
  float acc = 0.f;
#pragma unroll
  for (int k = 0; k < H1_; k += 4) {
    float4 hv = *(const float4*)(hr + k);
    acc = fmaf(hv.x, w_s[(k + 0) * H2_ + col], acc);
    acc = fmaf(hv.y, w_s[(k + 1) * H2_ + col], acc);
    acc = fmaf(hv.z, w_s[(k + 2) * H2_ + col], acc);
    acc = fmaf(hv.w, w_s[(k + 3) * H2_ + col], acc);
  }
  hw2[idx] = acc;
}

// ---- transpose + split-convert: in [B][N][H] fp32 -> out_hi/out_lo [B][H][N] bf16 ----
// hi = truncate-to-bf16(x); lo = truncate-to-bf16(x - hi)  (x - hi is exact in fp32)
template<int H>
__global__ __launch_bounds__(256) void k_t_cvt(const float* __restrict__ in,
                                               u16* __restrict__ out_hi,
                                               u16* __restrict__ out_lo) {
  __shared__ float s[64][H + 1];
  const int b = blockIdx.y;
  const int n0 = blockIdx.x * 64;
  const float* ip = in + ((size_t)b * N_ + n0) * H;
  constexpr int F4 = 64 * H / 4 / 256;          // float4 loads per thread
#pragma unroll
  for (int i = 0; i < F4; ++i) {
    int q = threadIdx.x + i * 256;
    int r = q / (H / 4), c4 = q % (H / 4);
    float4 v = *(const float4*)(ip + r * H + c4 * 4);
    s[r][c4 * 4 + 0] = v.x; s[r][c4 * 4 + 1] = v.y;
    s[r][c4 * 4 + 2] = v.z; s[r][c4 * 4 + 3] = v.w;
  }
  __syncthreads();
  constexpr int PASSES = H * 8 / 256;           // (H rows) x (8 threads/row of 8 n each)
#pragma unroll
  for (int p = 0; p < PASSES; ++p) {
    int q = threadIdx.x + p * 256;
    int h = q >> 3, nn = (q & 7) * 8;
    uint4 hv, lv;
    u32 hw[4], lw[4];
#pragma unroll
    for (int j = 0; j < 4; ++j) {
      float e0 = s[nn + 2 * j][h], e1 = s[nn + 2 * j + 1][h];
      u32 u0 = __float_as_uint(e0), u1 = __float_as_uint(e1);
      hw[j] = (u1 & 0xFFFF0000u) | (u0 >> 16);
      float l0 = e0 - __uint_as_float(u0 & 0xFFFF0000u);
      float l1 = e1 - __uint_as_float(u1 & 0xFFFF0000u);
      lw[j] = (__float_as_uint(l1) & 0xFFFF0000u) | (__float_as_uint(l0) >> 16);
    }
    hv.x = hw[0]; hv.y = hw[1]; hv.z = hw[2]; hv.w = hw[3];
    lv.x = lw[0]; lv.y = lw[1]; lv.z = lw[2]; lv.w = lw[3];
    size_t o = ((size_t)b * H + h) * N_ + n0 + nn;
    *(uint4*)(out_hi + o) = hv;
    *(uint4*)(out_lo + o) = lv;
  }
}

// ---- split fp32->bf16 hi/lo of 8 floats held in two float4 ----
__device__ __forceinline__ void cvt_split(const float4 a, const float4 b,
                                          short8& hi, short8& lo) {
  union { short8 s; uint4 u; } Hh, Ll;
  float e[8] = {a.x, a.y, a.z, a.w, b.x, b.y, b.z, b.w};
  u32 hw[4], lw[4];
#pragma unroll
  for (int j = 0; j < 4; ++j) {
    u32 u0 = __float_as_uint(e[2 * j]), u1 = __float_as_uint(e[2 * j + 1]);
    hw[j] = (u1 & 0xFFFF0000u) | (u0 >> 16);
    float l0 = e[2 * j] - __uint_as_float(u0 & 0xFFFF0000u);
    float l1 = e[2 * j + 1] - __uint_as_float(u1 & 0xFFFF0000u);
    lw[j] = (__float_as_uint(l1) & 0xFFFF0000u) | (__float_as_uint(l0) >> 16);
  }
  Hh.u.x = hw[0]; Hh.u.y = hw[1]; Hh.u.z = hw[2]; Hh.u.w = hw[3];
  Ll.u.x = lw[0]; Ll.u.y = lw[1]; Ll.u.z = lw[2]; Ll.u.w = lw[3];
  hi = Hh.s; lo = Ll.s;
}

// -------- MFMA A-GEMM partials, latency-optimized --------
// One wave = 16 rows x 16 cols (NT=1). Grid z packs (K-split z, 16-col group ch):
// H1: 2048 blocks, H2: 4096 blocks -> 8 blocks/CU -> 32 waves/CU (100% cap).
// Even/odd 64-K loop double-buffers BOTH A and B fragments: loads for chunk i+1
// issue before compute of chunk i -> vmcnt(N>0), ~8 loads in flight per wave.
template<int H>
__global__ __launch_bounds__(256, 6) void k_agemm_mfma(const float* __restrict__ A,
                                                       const u16* __restrict__ Bth,
                                                       const u16* __restrict__ Btl,
                                                       float* __restrict__ P) {
  constexpr int CGRP = H / 16;
  const int z  = blockIdx.z / CGRP;          // K-split index
  const int ch = blockIdx.z % CGRP;          // 16-col group
  const int batch = blockIdx.y;
  const int lane = threadIdx.x & 63;
  const int wave = threadIdx.x >> 6;
  const int arow = blockIdx.x * 64 + wave * 16 + (lane & 15);
  const int kfrag = (lane >> 4) * 8;

  const float* Ap = A + (size_t)batch * N_ * N_ + (size_t)arow * N_ + z * KSEG_ + kfrag;
  const u16* bh0 = Bth + ((size_t)batch * H + ch * 16 + (lane & 15)) * N_ + z * KSEG_ + kfrag;
  const u16* bl0 = Btl + ((size_t)batch * H + ch * 16 + (lane & 15)) * N_ + z * KSEG_ + kfrag;

  f32x4 acc = (f32x4){0.f, 0.f, 0.f, 0.f};

  // buffer 0 preload (chunk 0)
  float4 a00 = *(const float4*)(Ap);
  float4 a01 = *(const float4*)(Ap + 4);
  uint4  b0h = *(const uint4*)(bh0);
  uint4  b0l = *(const uint4*)(bl0);
  float4 a10, a11; uint4 b1h, b1l;

  for (int kk = 0; kk < KSEG_; kk += 64) {
    // issue loads for chunk kk+32 into buffer 1
    a10 = *(const float4*)(Ap + kk + 32);
    a11 = *(const float4*)(Ap + kk + 36);
    b1h = *(const uint4*)(bh0 + kk + 32);
    b1l = *(const uint4*)(bl0 + kk + 32);
    {
      short8 ahi, alo;
      cvt_split(a00, a01, ahi, alo);
      union { short8 s; uint4 u; } bh, bl; bh.u = b0h; bl.u = b0l;
      acc = __builtin_amdgcn_mfma_f32_16x16x32_bf16(ahi, bh.s, acc, 0, 0, 0);
      acc = __builtin_amdgcn_mfma_f32_16x16x32_bf16(ahi, bl.s, acc, 0, 0, 0);
      acc = __builtin_amdgcn_mfma_f32_16x16x32_bf16(alo, bh.s, acc, 0, 0, 0);
    }
    // issue loads for chunk kk+64 into buffer 0
    if (kk + 64 < KSEG_) {
      a00 = *(const float4*)(Ap + kk + 64);
      a01 = *(const float4*)(Ap + kk + 68);
      b0h = *(const uint4*)(bh0 + kk + 64);
      b0l = *(const uint4*)(bl0 + kk + 64);
    }
    {
      short8 ahi, alo;
      cvt_split(a10, a11, ahi, alo);
      union { short8 s; uint4 u; } bh, bl; bh.u = b1h; bl.u = b1l;
      acc = __builtin_amdgcn_mfma_f32_16x16x32_bf16(ahi, bh.s, acc, 0, 0, 0);
      acc = __builtin_amdgcn_mfma_f32_16x16x32_bf16(ahi, bl.s, acc, 0, 0, 0);
      acc = __builtin_amdgcn_mfma_f32_16x16x32_bf16(alo, bh.s, acc, 0, 0, 0);
    }
  }
  // C/D layout (m89): col = lane&15, row = (lane>>4)*4 + j
  const int orow = blockIdx.x * 64 + wave * 16 + ((lane >> 4) << 2);
  float* pp = P + ((size_t)(z * B_ + batch) * N_ + orow) * H + ch * 16 + (lane & 15);
#pragma unroll
  for (int j = 0; j < 4; ++j)
    pp[(size_t)j * H] = acc[j];
}

// -------- reduce KS partials + bias + relu (vectorized float4) --------
template<int H>
__global__ __launch_bounds__(256) void k_part_reduce(const float* __restrict__ part,
                                                     const float* __restrict__ bias,
                                                     float* __restrict__ out) {
  constexpr int TOT4 = B_ * N_ * H / 4;
  int idx = blockIdx.x * 256 + threadIdx.x;
  const float4* p4 = (const float4*)part;
  float4 s  = p4[idx];
  float4 t1 = p4[idx + TOT4];
  float4 t2 = p4[idx + 2 * TOT4];
  float4 t3 = p4[idx + 3 * TOT4];
  float4 bv = ((const float4*)bias)[idx % (H / 4)];
  float4 o;
  o.x = fmaxf(s.x + t1.x + t2.x + t3.x + bv.x, 0.f);
  o.y = fmaxf(s.y + t1.y + t2.y + t3.y + bv.y, 0.f);
  o.z = fmaxf(s.z + t1.z + t2.z + t3.z + bv.z, 0.f);
  o.w = fmaxf(s.w + t1.w + t2.w + t3.w + bv.w, 0.f);
  ((float4*)out)[idx] = o;
}

// -------- dense 5a: K-split partials of flat(h2) @ Wd; Wd streamed once --------
__global__ __launch_bounds__(512) void k_dense_part(const float* __restrict__ h2,
                                                    const float* __restrict__ Wd,
                                                    float* __restrict__ part) {
  constexpr int KC = 512;                  // K rows per block; grid = 131072/512 = 256
  __shared__ float hs[B_][KC];
  __shared__ float psum[B_][D1_];
  const int kc0 = blockIdx.x * KC;
  const int tid = threadIdx.x;
#pragma unroll
  for (int i = 0; i < 2; ++i) {            // stage 8 x 512 floats, coalesced
    int q = tid + i * 512;
    int b = q >> 7, kq = (q & 127) * 4;
    *(float4*)&hs[b][kq] = *(const float4*)(h2 + (size_t)b * (N_ * H2_) + kc0 + kq);
  }
  __syncthreads();
  const int d0 = (tid & 31) * 4;           // 4 output cols
  const int b  = (tid >> 5) & 7;           // batch
  const int ks = tid >> 8;                 // in-block k-split (0/1)
  float a0 = 0.f, a1 = 0.f, a2 = 0.f, a3 = 0.f;
  const float* wp = Wd + ((size_t)kc0 + ks * 256) * D1_ + d0;
  const float* hp = &hs[b][ks * 256];
#pragma unroll 4
  for (int k = 0; k < 256; ++k) {
    float4 w = *(const float4*)(wp + (size_t)k * D1_);
    float h = hp[k];
    a0 = fmaf(h, w.x, a0); a1 = fmaf(h, w.y, a1);
    a2 = fmaf(h, w.z, a2); a3 = fmaf(h, w.w, a3);
  }
  if (ks == 1) {
    psum[b][d0] = a0; psum[b][d0 + 1] = a1; psum[b][d0 + 2] = a2; psum[b][d0 + 3] = a3;
  }
  __syncthreads();
  if (ks == 0) {
    float* pp = part + ((size_t)blockIdx.x * B_ + b) * D1_ + d0;
    *(float4*)pp = make_float4(a0 + psum[b][d0], a1 + psum[b][d0 + 1],
                               a2 + psum[b][d0 + 2], a3 + psum[b][d0 + 3]);
  }
}

// -------- dense 5b: reduce partials + bias + relu -> hd [8,128] --------
__global__ __launch_bounds__(256) void k_dense_reduce(const float* __restrict__ part,
                                                      const float* __restrict__ bd,
                                                      float* __restrict__ hd) {
  int idx = blockIdx.x * 256 + threadIdx.x;   // 0..1023 = b*128+d
  float s = 0.f;
  for (int i = 0; i < 256; ++i) s += part[(size_t)i * (B_ * D1_) + idx];
  hd[idx] = fmaxf(s + bd[idx & (D1_ - 1)], 0.f);
}

// -------- kernel 6: out[b] = sigmoid(hd[b,:] . Wo + bo) --------
__global__ __launch_bounds__(512) void k_final(const float* __restrict__ hd,
                                               const float* __restrict__ Wo,
                                               const float* __restrict__ bo,
                                               float* __restrict__ out) {
  int w = threadIdx.x >> 6;   // wave id = batch
  int l = threadIdx.x & 63;
  float v = hd[w * D1_ + l] * Wo[l] + hd[w * D1_ + 64 + l] * Wo[64 + l];
#pragma unroll
  for (int off = 32; off; off >>= 1) v += __shfl_down(v, off, 64);
  if (l == 0) out[w] = 1.f / (1.f + expf(-(v + bo[0])));
}

extern "C" void kernel_launch(void* const* d_in, const int* in_sizes, int n_in,
                              void* d_out, int out_size, void* d_ws, size_t ws_size,
                              hipStream_t stream) {
  const float* x  = (const float*)d_in[0];
  const float* a  = (const float*)d_in[1];
  const float* W1 = (const float*)d_in[2];
  const float* b1 = (const float*)d_in[3];
  const float* W2 = (const float*)d_in[4];
  const float* b2 = (const float*)d_in[5];
  const float* Wd = (const float*)d_in[6];
  const float* bd = (const float*)d_in[7];
  const float* Wo = (const float*)d_in[8];
  const float* bo = (const float*)d_in[9];
  float* out = (float*)d_out;

  // workspace (floats), lifetime-aliased; total 6,291,456 floats = 25.2 MB:
  //  [0, 4194304)          P (agemm partials)    | hw2 (before agemm2) | dpart+hd (after)
  //  [4194304, 4718592)    xw1                   | h2 [4194304,5242880) later
  //  [4718592, 5242880)    h1
  //  [5242880, 6291456)    Bt1 hi/lo (pass1)     | Bt2 hi/lo (pass2)
  float* ws   = (float*)d_ws;
  float* P    = ws;
  float* hw2  = ws;                        // alias P (P pass-1 dead by then)
  float* xw1  = ws + 4194304;
  float* h1   = ws + 4718592;
  float* h2   = ws + 4194304;              // alias xw1+h1 (both dead)
  u16*   Bt1h = (u16*)(ws + 5242880);
  u16*   Bt1l = (u16*)(ws + 5505024);
  u16*   Bt2h = (u16*)(ws + 5242880);      // alias Bt1 (dead)
  u16*   Bt2l = (u16*)(ws + 5767168);
  float* dpart = ws;                       // alias P (dead)
  float* hd   = ws + 262144;

  k_xw1<<<(B_ * N_ * H1_) / 256, 256, 0, stream>>>(x, W1, xw1);
  k_t_cvt<H1_><<<dim3(N_ / 64, B_), 256, 0, stream>>>(xw1, Bt1h, Bt1l);
  k_agemm_mfma<H1_><<<dim3(N_ / 64, B_, KS_ * (H1_ / 16)), 256, 0, stream>>>(a, Bt1h, Bt1l, P);
  k_part_reduce<H1_><<<(B_ * N_ * H1_ / 4) / 256, 256, 0, stream>>>(P, b1, h1);
  k_hw2<<<(B_ * N_ * H2_) / 256, 256, 0, stream>>>(h1, W2, hw2);
  k_t_cvt<H2_><<<dim3(N_ / 64, B_), 256, 0, stream>>>(hw2, Bt2h, Bt2l);
  k_agemm_mfma<H2_><<<dim3(N_ / 64, B_, KS_ * (H2_ / 16)), 256, 0, stream>>>(a, Bt2h, Bt2l, P);
  k_part_reduce<H2_><<<(B_ * N_ * H2_ / 4) / 256, 256, 0, stream>>>(P, b2, h2);
  k_dense_part<<<(N_ * H2_) / 512, 512, 0, stream>>>(h2, Wd, dpart);
  k_dense_reduce<<<4, 256, 0, stream>>>(dpart, bd, hd);
  k_final<<<1, 512, 0, stream>>>(hd, Wo, bo, out);
}

// Round 8
// 138.552 us; speedup vs baseline: 1.7703x; 1.7703x over previous
//
#include <hip/hip_runtime.h>
#include <math.h>

#define B_  8
#define N_  2048
#define F_  128
#define H1_ 32
#define H2_ 64
#define D1_ 128
#define KS_ 4            // K-split factor for the A-GEMMs
#define KSEG_ (N_ / KS_) // 512 K per block

typedef unsigned short u16;
typedef unsigned int   u32;
typedef __attribute__((ext_vector_type(8))) short short8;  // 8 bf16 (4 VGPRs)
typedef __attribute__((ext_vector_type(4))) float f32x4;

// ---------------- kernel 1: xw1 = x @ W1   [B*N,128] @ [128,32] ----------------
__global__ __launch_bounds__(256) void k_xw1(const float* __restrict__ x,
                                             const float* __restrict__ W1,
                                             float* __restrict__ xw1) {
  __shared__ float w_s[F_ * H1_];
  for (int i = threadIdx.x; i < F_ * H1_; i += 256) w_s[i] = W1[i];
  __syncthreads();
  int idx = blockIdx.x * 256 + threadIdx.x;     // over B*N*H1
  int row = idx >> 5, col = idx & 31;
  const float* xr = x + (size_t)row * F_;
  float acc = 0.f;
#pragma unroll
  for (int k = 0; k < F_; k += 4) {
    float4 xv = *(const float4*)(xr + k);
    acc = fmaf(xv.x, w_s[(k + 0) * H1_ + col], acc);
    acc = fmaf(xv.y, w_s[(k + 1) * H1_ + col], acc);
    acc = fmaf(xv.z, w_s[(k + 2) * H1_ + col], acc);
    acc = fmaf(xv.w, w_s[(k + 3) * H1_ + col], acc);
  }
  xw1[idx] = acc;
}

// ---------------- kernel: hw2 = h1 @ W2   [B*N,32] @ [32,64] ----------------
__global__ __launch_bounds__(256) void k_hw2(const float* __restrict__ h1,
                                             const float* __restrict__ W2,
                                             float* __restrict__ hw2) {
  __shared__ float w_s[H1_ * H2_];
  for (int i = threadIdx.x; i < H1_ * H2_; i += 256) w_s[i] = W2[i];
  __syncthreads();
  int idx = blockIdx.x * 256 + threadIdx.x;     // over B*N*H2
  int row = idx >> 6, col = idx & 63;
  const float* hr = h1 + (size_t)row * H1_;
  float acc = 0.f;
#pragma unroll
  for (int k = 0; k < H1_; k += 4) {
    float4 hv = *(const float4*)(hr + k);
    acc = fmaf(hv.x, w_s[(k + 0) * H2_ + col], acc);
    acc = fmaf(hv.y, w_s[(k + 1) * H2_ + col], acc);
    acc = fmaf(hv.z, w_s[(k + 2) * H2_ + col], acc);
    acc = fmaf(hv.w, w_s[(k + 3) * H2_ + col], acc);
  }
  hw2[idx] = acc;
}

// ---- transpose + split-convert + PACK into MFMA B-fragment order ----
// in [B][N][H] fp32 -> packed hi/lo bf16: for (b, colgrp ch, chunk c):
// 64 lanes x 8 bf16, lane = slot*16 + (h&15), holds B[k = c*32+slot*8+i][col].
// Agemm then loads each B-frag as ONE uint4 at base+lane*16 (dense, 8 txns).
template<int H>
__global__ __launch_bounds__(256) void k_t_cvt(const float* __restrict__ in,
                                               u16* __restrict__ out_hi,
                                               u16* __restrict__ out_lo) {
  constexpr int CGRP = H / 16;
  __shared__ float s[64][H + 1];
  const int b = blockIdx.y;
  const int n0 = blockIdx.x * 64;
  const float* ip = in + ((size_t)b * N_ + n0) * H;
  constexpr int F4 = 64 * H / 4 / 256;          // float4 loads per thread
#pragma unroll
  for (int i = 0; i < F4; ++i) {
    int q = threadIdx.x + i * 256;
    int r = q / (H / 4), c4 = q % (H / 4);
    float4 v = *(const float4*)(ip + r * H + c4 * 4);
    s[r][c4 * 4 + 0] = v.x; s[r][c4 * 4 + 1] = v.y;
    s[r][c4 * 4 + 2] = v.z; s[r][c4 * 4 + 3] = v.w;
  }
  __syncthreads();
  constexpr int PASSES = H * 8 / 256;           // (H cols) x (8 threads/col of 8 n each)
#pragma unroll
  for (int p = 0; p < PASSES; ++p) {
    int q = threadIdx.x + p * 256;
    int h = q >> 3, nn = (q & 7) * 8;           // 8 consecutive n for col h
    u32 hw[4], lw[4];
#pragma unroll
    for (int j = 0; j < 4; ++j) {
      float e0 = s[nn + 2 * j][h], e1 = s[nn + 2 * j + 1][h];
      u32 u0 = __float_as_uint(e0), u1 = __float_as_uint(e1);
      hw[j] = (u1 & 0xFFFF0000u) | (u0 >> 16);
      float l0 = e0 - __uint_as_float(u0 & 0xFFFF0000u);
      float l1 = e1 - __uint_as_float(u1 & 0xFFFF0000u);
      lw[j] = (__float_as_uint(l1) & 0xFFFF0000u) | (__float_as_uint(l0) >> 16);
    }
    uint4 hv = make_uint4(hw[0], hw[1], hw[2], hw[3]);
    uint4 lv = make_uint4(lw[0], lw[1], lw[2], lw[3]);
    // packed fragment address
    int ch = h >> 4, cl = h & 15;
    int cg = blockIdx.x * 2 + (nn >> 5);        // global 32-chunk index
    int slot = (nn >> 3) & 3;
    int lanep = slot * 16 + cl;
    size_t o = ((((size_t)b * CGRP + ch) * (N_ / 32) + cg) * 64 + lanep) * 8;
    *(uint4*)(out_hi + o) = hv;
    *(uint4*)(out_lo + o) = lv;
  }
}

// ---- split fp32->bf16 hi/lo of 8 floats held in two float4 ----
__device__ __forceinline__ void cvt_split(const float4 a, const float4 b,
                                          short8& hi, short8& lo) {
  union { short8 s; uint4 u; } Hh, Ll;
  float e[8] = {a.x, a.y, a.z, a.w, b.x, b.y, b.z, b.w};
  u32 hw[4], lw[4];
#pragma unroll
  for (int j = 0; j < 4; ++j) {
    u32 u0 = __float_as_uint(e[2 * j]), u1 = __float_as_uint(e[2 * j + 1]);
    hw[j] = (u1 & 0xFFFF0000u) | (u0 >> 16);
    float l0 = e[2 * j] - __uint_as_float(u0 & 0xFFFF0000u);
    float l1 = e[2 * j + 1] - __uint_as_float(u1 & 0xFFFF0000u);
    lw[j] = (__float_as_uint(l1) & 0xFFFF0000u) | (__float_as_uint(l0) >> 16);
  }
  Hh.u.x = hw[0]; Hh.u.y = hw[1]; Hh.u.z = hw[2]; Hh.u.w = hw[3];
  Ll.u.x = lw[0]; Ll.u.y = lw[1]; Ll.u.z = lw[2]; Ll.u.w = lw[3];
  hi = Hh.s; lo = Ll.s;
}

// -------- MFMA A-GEMM partials, LDS-staged A + packed B --------
// Grid (N/64, B, KS) = 1024 blocks, 4 waves. Wave w = rows w*16..w*16+15, all H cols.
// A tile [64][BK=64] fp32 reg-staged into padded LDS [64][68], double-buffered:
// loads issued at iteration start (sched_barrier pins them), ds_write after
// compute -> 16 KB/block in flight under the MFMA phase. Staging loads are
// dense (16-lane group = one row's 256 B). B-frags are single uint4 at
// base+lane*16 from the packed layout (L2-resident).
template<int H>
__global__ __launch_bounds__(256, 4) void k_agemm_mfma(const float* __restrict__ A,
                                                       const u16* __restrict__ Bph,
                                                       const u16* __restrict__ Bpl,
                                                       float* __restrict__ P) {
  constexpr int NT = H / 16;
  constexpr int BK = 64;
  constexpr int NTILE = KSEG_ / BK;            // 8
  __shared__ float at[2][64][68];

  const int batch = blockIdx.y;
  const int z = blockIdx.z;
  const int m0 = blockIdx.x * 64;
  const int tid = threadIdx.x;
  const int lane = tid & 63;
  const int wave = tid >> 6;

  const float* Ab = A + (size_t)batch * N_ * N_ + (size_t)m0 * N_ + (size_t)z * KSEG_;
  const int srow = tid >> 4, scol = tid & 15;  // staging: 4 rows x 16B slot each

  const size_t cg0 = (size_t)z * (KSEG_ / 32); // first 32-chunk of this K segment
  const u16* bhb = Bph + ((size_t)batch * NT) * (N_ / 32) * 512 + (size_t)lane * 8;
  const u16* blb = Bpl + ((size_t)batch * NT) * (N_ / 32) * 512 + (size_t)lane * 8;

  float4 st[4];
#pragma unroll
  for (int i = 0; i < 4; ++i)
    st[i] = *(const float4*)(Ab + (size_t)(srow + 16 * i) * N_ + scol * 4);
#pragma unroll
  for (int i = 0; i < 4; ++i)
    *(float4*)&at[0][srow + 16 * i][scol * 4] = st[i];
  __syncthreads();

  f32x4 acc[NT];
#pragma unroll
  for (int c = 0; c < NT; ++c) acc[c] = (f32x4){0.f, 0.f, 0.f, 0.f};

  for (int t = 0; t < NTILE; ++t) {
    const int kk = t * BK;
    const int buf = t & 1;
    if (t + 1 < NTILE) {                       // issue next-tile loads EARLY
#pragma unroll
      for (int i = 0; i < 4; ++i)
        st[i] = *(const float4*)(Ab + (size_t)(srow + 16 * i) * N_ + (kk + BK) + scol * 4);
      __builtin_amdgcn_sched_barrier(0);       // pin: loads must not sink
    }
#pragma unroll
    for (int c = 0; c < 2; ++c) {              // two 32-K chunks per tile
      const float* ar = &at[buf][wave * 16 + (lane & 15)][c * 32 + (lane >> 4) * 8];
      float4 a0 = *(const float4*)ar;
      float4 a1 = *(const float4*)(ar + 4);
      short8 ahi, alo;
      cvt_split(a0, a1, ahi, alo);
      const size_t co = (cg0 + (kk >> 5) + c) * 512;
#pragma unroll
      for (int ch = 0; ch < NT; ++ch) {
        union { short8 s; uint4 u; } bh, bl;
        bh.u = *(const uint4*)(bhb + ((size_t)ch * (N_ / 32)) * 512 + co);
        bl.u = *(const uint4*)(blb + ((size_t)ch * (N_ / 32)) * 512 + co);
        acc[ch] = __builtin_amdgcn_mfma_f32_16x16x32_bf16(ahi, bh.s, acc[ch], 0, 0, 0);
        acc[ch] = __builtin_amdgcn_mfma_f32_16x16x32_bf16(ahi, bl.s, acc[ch], 0, 0, 0);
        acc[ch] = __builtin_amdgcn_mfma_f32_16x16x32_bf16(alo, bh.s, acc[ch], 0, 0, 0);
      }
    }
    if (t + 1 < NTILE) {                       // write staged regs to other buffer
#pragma unroll
      for (int i = 0; i < 4; ++i)
        *(float4*)&at[buf ^ 1][srow + 16 * i][scol * 4] = st[i];
    }
    __syncthreads();
  }
  // C/D layout (m89): col = lane&15, row = (lane>>4)*4 + j
  const int orow = m0 + wave * 16 + ((lane >> 4) << 2);
  float* pp = P + ((size_t)(z * B_ + batch) * N_ + orow) * H + (lane & 15);
#pragma unroll
  for (int ch = 0; ch < NT; ++ch)
#pragma unroll
    for (int j = 0; j < 4; ++j)
      pp[(size_t)j * H + ch * 16] = acc[ch][j];
}

// -------- reduce KS partials + bias + relu (vectorized float4) --------
template<int H>
__global__ __launch_bounds__(256) void k_part_reduce(const float* __restrict__ part,
                                                     const float* __restrict__ bias,
                                                     float* __restrict__ out) {
  constexpr int TOT4 = B_ * N_ * H / 4;
  int idx = blockIdx.x * 256 + threadIdx.x;
  const float4* p4 = (const float4*)part;
  float4 s  = p4[idx];
  float4 t1 = p4[idx + TOT4];
  float4 t2 = p4[idx + 2 * TOT4];
  float4 t3 = p4[idx + 3 * TOT4];
  float4 bv = ((const float4*)bias)[idx % (H / 4)];
  float4 o;
  o.x = fmaxf(s.x + t1.x + t2.x + t3.x + bv.x, 0.f);
  o.y = fmaxf(s.y + t1.y + t2.y + t3.y + bv.y, 0.f);
  o.z = fmaxf(s.z + t1.z + t2.z + t3.z + bv.z, 0.f);
  o.w = fmaxf(s.w + t1.w + t2.w + t3.w + bv.w, 0.f);
  ((float4*)out)[idx] = o;
}

// -------- dense 5a: K-split partials of flat(h2) @ Wd; Wd streamed once --------
__global__ __launch_bounds__(512) void k_dense_part(const float* __restrict__ h2,
                                                    const float* __restrict__ Wd,
                                                    float* __restrict__ part) {
  constexpr int KC = 512;                  // K rows per block; grid = 131072/512 = 256
  __shared__ float hs[B_][KC];
  __shared__ float psum[B_][D1_];
  const int kc0 = blockIdx.x * KC;
  const int tid = threadIdx.x;
#pragma unroll
  for (int i = 0; i < 2; ++i) {            // stage 8 x 512 floats, coalesced
    int q = tid + i * 512;
    int b = q >> 7, kq = (q & 127) * 4;
    *(float4*)&hs[b][kq] = *(const float4*)(h2 + (size_t)b * (N_ * H2_) + kc0 + kq);
  }
  __syncthreads();
  const int d0 = (tid & 31) * 4;           // 4 output cols
  const int b  = (tid >> 5) & 7;           // batch
  const int ks = tid >> 8;                 // in-block k-split (0/1)
  float a0 = 0.f, a1 = 0.f, a2 = 0.f, a3 = 0.f;
  const float* wp = Wd + ((size_t)kc0 + ks * 256) * D1_ + d0;
  const float* hp = &hs[b][ks * 256];
#pragma unroll 4
  for (int k = 0; k < 256; ++k) {
    float4 w = *(const float4*)(wp + (size_t)k * D1_);
    float h = hp[k];
    a0 = fmaf(h, w.x, a0); a1 = fmaf(h, w.y, a1);
    a2 = fmaf(h, w.z, a2); a3 = fmaf(h, w.w, a3);
  }
  if (ks == 1) {
    psum[b][d0] = a0; psum[b][d0 + 1] = a1; psum[b][d0 + 2] = a2; psum[b][d0 + 3] = a3;
  }
  __syncthreads();
  if (ks == 0) {
    float* pp = part + ((size_t)blockIdx.x * B_ + b) * D1_ + d0;
    *(float4*)pp = make_float4(a0 + psum[b][d0], a1 + psum[b][d0 + 1],
                               a2 + psum[b][d0 + 2], a3 + psum[b][d0 + 3]);
  }
}

// -------- dense 5b: reduce partials + bias + relu -> hd [8,128] --------
__global__ __launch_bounds__(256) void k_dense_reduce(const float* __restrict__ part,
                                                      const float* __restrict__ bd,
                                                      float* __restrict__ hd) {
  int idx = blockIdx.x * 256 + threadIdx.x;   // 0..1023 = b*128+d
  float s = 0.f;
  for (int i = 0; i < 256; ++i) s += part[(size_t)i * (B_ * D1_) + idx];
  hd[idx] = fmaxf(s + bd[idx & (D1_ - 1)], 0.f);
}

// -------- kernel 6: out[b] = sigmoid(hd[b,:] . Wo + bo) --------
__global__ __launch_bounds__(512) void k_final(const float* __restrict__ hd,
                                               const float* __restrict__ Wo,
                                               const float* __restrict__ bo,
                                               float* __restrict__ out) {
  int w = threadIdx.x >> 6;   // wave id = batch
  int l = threadIdx.x & 63;
  float v = hd[w * D1_ + l] * Wo[l] + hd[w * D1_ + 64 + l] * Wo[64 + l];
#pragma unroll
  for (int off = 32; off; off >>= 1) v += __shfl_down(v, off, 64);
  if (l == 0) out[w] = 1.f / (1.f + expf(-(v + bo[0])));
}

extern "C" void kernel_launch(void* const* d_in, const int* in_sizes, int n_in,
                              void* d_out, int out_size, void* d_ws, size_t ws_size,
                              hipStream_t stream) {
  const float* x  = (const float*)d_in[0];
  const float* a  = (const float*)d_in[1];
  const float* W1 = (const float*)d_in[2];
  const float* b1 = (const float*)d_in[3];
  const float* W2 = (const float*)d_in[4];
  const float* b2 = (const float*)d_in[5];
  const float* Wd = (const float*)d_in[6];
  const float* bd = (const float*)d_in[7];
  const float* Wo = (const float*)d_in[8];
  const float* bo = (const float*)d_in[9];
  float* out = (float*)d_out;

  // workspace (floats), lifetime-aliased; total 6,291,456 floats = 25.2 MB:
  //  [0, 4194304)          P (agemm partials)    | hw2 (before agemm2) | dpart+hd (after)
  //  [4194304, 4718592)    xw1                   | h2 [4194304,5242880) later
  //  [4718592, 5242880)    h1
  //  [5242880, 6291456)    Bt1 hi/lo (pass1)     | Bt2 hi/lo (pass2)
  float* ws   = (float*)d_ws;
  float* P    = ws;
  float* hw2  = ws;                        // alias P (P pass-1 dead by then)
  float* xw1  = ws + 4194304;
  float* h1   = ws + 4718592;
  float* h2   = ws + 4194304;              // alias xw1/h1 (both dead)
  u16*   Bt1h = (u16*)(ws + 5242880);
  u16*   Bt1l = (u16*)(ws + 5505024);
  u16*   Bt2h = (u16*)(ws + 5242880);      // alias Bt1 (dead)
  u16*   Bt2l = (u16*)(ws + 5767168);
  float* dpart = ws;                       // alias P (dead)
  float* hd   = ws + 262144;

  k_xw1<<<(B_ * N_ * H1_) / 256, 256, 0, stream>>>(x, W1, xw1);
  k_t_cvt<H1_><<<dim3(N_ / 64, B_), 256, 0, stream>>>(xw1, Bt1h, Bt1l);
  k_agemm_mfma<H1_><<<dim3(N_ / 64, B_, KS_), 256, 0, stream>>>(a, Bt1h, Bt1l, P);
  k_part_reduce<H1_><<<(B_ * N_ * H1_ / 4) / 256, 256, 0, stream>>>(P, b1, h1);
  k_hw2<<<(B_ * N_ * H2_) / 256, 256, 0, stream>>>(h1, W2, hw2);
  k_t_cvt<H2_><<<dim3(N_ / 64, B_), 256, 0, stream>>>(hw2, Bt2h, Bt2l);
  k_agemm_mfma<H2_><<<dim3(N_ / 64, B_, KS_), 256, 0, stream>>>(a, Bt2h, Bt2l, P);
  k_part_reduce<H2_><<<(B_ * N_ * H2_ / 4) / 256, 256, 0, stream>>>(P, b2, h2);
  k_dense_part<<<(N_ * H2_) / 512, 512, 0, stream>>>(h2, Wd, dpart);
  k_dense_reduce<<<4, 256, 0, stream>>>(dpart, bd, hd);
  k_final<<<1, 512, 0, stream>>>(hd, Wo, bo, out);
}

// Round 9
// 117.809 us; speedup vs baseline: 2.0820x; 1.1761x over previous
//
#include <hip/hip_runtime.h>
#include <math.h>

#define B_  8
#define N_  2048
#define F_  128
#define H1_ 32
#define H2_ 64
#define D1_ 128
#define KS_ 4            // K-split factor for the A-GEMMs
#define KSEG_ (N_ / KS_) // 512 K per block

typedef unsigned short u16;
typedef unsigned int   u32;
typedef __attribute__((ext_vector_type(8))) short short8;  // 8 bf16 (4 VGPRs)
typedef __attribute__((ext_vector_type(4))) float f32x4;

// ---- split fp32->bf16 hi/lo of 8 floats held in two float4 ----
__device__ __forceinline__ void cvt_split(const float4 a, const float4 b,
                                          short8& hi, short8& lo) {
  union { short8 s; uint4 u; } Hh, Ll;
  float e[8] = {a.x, a.y, a.z, a.w, b.x, b.y, b.z, b.w};
  u32 hw[4], lw[4];
#pragma unroll
  for (int j = 0; j < 4; ++j) {
    u32 u0 = __float_as_uint(e[2 * j]), u1 = __float_as_uint(e[2 * j + 1]);
    hw[j] = (u1 & 0xFFFF0000u) | (u0 >> 16);
    float l0 = e[2 * j] - __uint_as_float(u0 & 0xFFFF0000u);
    float l1 = e[2 * j + 1] - __uint_as_float(u1 & 0xFFFF0000u);
    lw[j] = (__float_as_uint(l1) & 0xFFFF0000u) | (__float_as_uint(l0) >> 16);
  }
  Hh.u.x = hw[0]; Hh.u.y = hw[1]; Hh.u.z = hw[2]; Hh.u.w = hw[3];
  Ll.u.x = lw[0]; Ll.u.y = lw[1]; Ll.u.z = lw[2]; Ll.u.w = lw[3];
  hi = Hh.s; lo = Ll.s;
}

// ---- pack a [64][LDST] fp32 LDS tile (rows = n, cols = h) into MFMA B-frag
// order, split to hi/lo bf16. Same layout the agemm consumes:
// frag (b, ch, cg): 64 lanes x 8 bf16, lane = slot*16+cl holds B[k=cg*32+slot*8+i][col].
template<int H, int LDST>
__device__ __forceinline__ void pack_frags(const float* s, int b, int cgbase,
                                           u16* __restrict__ oh, u16* __restrict__ ol,
                                           int tid) {
  constexpr int CGRP = H / 16;
  constexpr int PASSES = H * 8 / 256;
#pragma unroll
  for (int p = 0; p < PASSES; ++p) {
    int q = tid + p * 256;
    int h = q >> 3, nn = (q & 7) * 8;           // 8 consecutive n for col h
    u32 hw[4], lw[4];
#pragma unroll
    for (int j = 0; j < 4; ++j) {
      float e0 = s[(nn + 2 * j) * LDST + h], e1 = s[(nn + 2 * j + 1) * LDST + h];
      u32 u0 = __float_as_uint(e0), u1 = __float_as_uint(e1);
      hw[j] = (u1 & 0xFFFF0000u) | (u0 >> 16);
      float l0 = e0 - __uint_as_float(u0 & 0xFFFF0000u);
      float l1 = e1 - __uint_as_float(u1 & 0xFFFF0000u);
      lw[j] = (__float_as_uint(l1) & 0xFFFF0000u) | (__float_as_uint(l0) >> 16);
    }
    int ch = h >> 4, cl = h & 15;
    int cg = cgbase + (nn >> 5);
    int lanep = ((nn >> 3) & 3) * 16 + cl;
    size_t o = ((((size_t)b * CGRP + ch) * (N_ / 32) + cg) * 64 + lanep) * 8;
    *(uint4*)(oh + o) = make_uint4(hw[0], hw[1], hw[2], hw[3]);
    *(uint4*)(ol + o) = make_uint4(lw[0], lw[1], lw[2], lw[3]);
  }
}

// -------- fused: xw1 = x @ W1 (64-row tile), then split/pack for agemm --------
__global__ __launch_bounds__(256) void k_xw1cvt(const float* __restrict__ x,
                                                const float* __restrict__ W1,
                                                u16* __restrict__ oh,
                                                u16* __restrict__ ol) {
  __shared__ float xs[64][F_];        // 32 KB
  __shared__ float w1s[F_ * H1_];     // 16 KB
  __shared__ float s[64][H1_ + 1];    // 8.4 KB
  const int b = blockIdx.y;
  const int n0 = blockIdx.x * 64;
  const int tid = threadIdx.x;
  const float* xp = x + ((size_t)b * N_ + n0) * F_;
#pragma unroll
  for (int i = 0; i < 8; ++i) {       // stage x tile: 8192 floats
    int q = tid + i * 256;
    int r = q >> 5, c4 = (q & 31) * 4;
    *(float4*)&xs[r][c4] = *(const float4*)(xp + (size_t)r * F_ + c4);
  }
#pragma unroll
  for (int i = 0; i < 4; ++i)         // stage W1: 4096 floats
    ((float4*)w1s)[tid + i * 256] = ((const float4*)W1)[tid + i * 256];
  __syncthreads();
  const int r = tid >> 2, c0 = (tid & 3) * 8;
  float acc[8] = {};
#pragma unroll
  for (int k = 0; k < F_; ++k) {
    float xv = xs[r][k];
#pragma unroll
    for (int j = 0; j < 8; ++j)
      acc[j] = fmaf(xv, w1s[k * H1_ + c0 + j], acc[j]);
  }
#pragma unroll
  for (int j = 0; j < 8; ++j) s[r][c0 + j] = acc[j];
  __syncthreads();
  pack_frags<H1_, H1_ + 1>(&s[0][0], b, blockIdx.x * 2, oh, ol, tid);
}

// -------- fused: h1 = relu(sum_z P1 + b1); hw2 = h1 @ W2; split/pack --------
__global__ __launch_bounds__(256) void k_l1fuse(const float* __restrict__ P1,
                                                const float* __restrict__ b1,
                                                const float* __restrict__ W2,
                                                u16* __restrict__ oh,
                                                u16* __restrict__ ol) {
  __shared__ float h1s[64][H1_ + 1];   // 8.4 KB
  __shared__ float w2s[H1_ * H2_];     // 8 KB
  __shared__ float hw2s[64][H2_ + 1];  // 16.6 KB
  const int b = blockIdx.y;
  const int n0 = blockIdx.x * 64;
  const int tid = threadIdx.x;
  constexpr int TOT = B_ * N_ * H1_;   // one z-slice
#pragma unroll
  for (int i = 0; i < 2; ++i) {        // reduce 4 partials + bias + relu
    int q = tid + i * 256;
    int r = q >> 3, h4 = (q & 7) * 4;
    size_t base = (((size_t)b * N_) + n0 + r) * H1_ + h4;
    float4 v0 = *(const float4*)(P1 + base);
    float4 v1 = *(const float4*)(P1 + base + TOT);
    float4 v2 = *(const float4*)(P1 + base + 2 * (size_t)TOT);
    float4 v3 = *(const float4*)(P1 + base + 3 * (size_t)TOT);
    float4 bv = *(const float4*)(b1 + h4);
    h1s[r][h4 + 0] = fmaxf(v0.x + v1.x + v2.x + v3.x + bv.x, 0.f);
    h1s[r][h4 + 1] = fmaxf(v0.y + v1.y + v2.y + v3.y + bv.y, 0.f);
    h1s[r][h4 + 2] = fmaxf(v0.z + v1.z + v2.z + v3.z + bv.z, 0.f);
    h1s[r][h4 + 3] = fmaxf(v0.w + v1.w + v2.w + v3.w + bv.w, 0.f);
  }
#pragma unroll
  for (int i = 0; i < 2; ++i)          // stage W2: 2048 floats
    ((float4*)w2s)[tid + i * 256] = ((const float4*)W2)[tid + i * 256];
  __syncthreads();
  const int r = tid >> 2, c0 = (tid & 3) * 16;
  float acc[16] = {};
#pragma unroll
  for (int k = 0; k < H1_; ++k) {
    float hv = h1s[r][k];
#pragma unroll
    for (int j = 0; j < 16; ++j)
      acc[j] = fmaf(hv, w2s[k * H2_ + c0 + j], acc[j]);
  }
#pragma unroll
  for (int j = 0; j < 16; ++j) hw2s[r][c0 + j] = acc[j];
  __syncthreads();
  pack_frags<H2_, H2_ + 1>(&hw2s[0][0], b, blockIdx.x * 2, oh, ol, tid);
}

// -------- MFMA A-GEMM partials, LDS-staged A + packed B (unchanged) --------
template<int H>
__global__ __launch_bounds__(256, 4) void k_agemm_mfma(const float* __restrict__ A,
                                                       const u16* __restrict__ Bph,
                                                       const u16* __restrict__ Bpl,
                                                       float* __restrict__ P) {
  constexpr int NT = H / 16;
  constexpr int BK = 64;
  constexpr int NTILE = KSEG_ / BK;            // 8
  __shared__ float at[2][64][68];

  const int batch = blockIdx.y;
  const int z = blockIdx.z;
  const int m0 = blockIdx.x * 64;
  const int tid = threadIdx.x;
  const int lane = tid & 63;
  const int wave = tid >> 6;

  const float* Ab = A + (size_t)batch * N_ * N_ + (size_t)m0 * N_ + (size_t)z * KSEG_;
  const int srow = tid >> 4, scol = tid & 15;  // staging: 4 rows x 16B slot each

  const size_t cg0 = (size_t)z * (KSEG_ / 32); // first 32-chunk of this K segment
  const u16* bhb = Bph + ((size_t)batch * NT) * (N_ / 32) * 512 + (size_t)lane * 8;
  const u16* blb = Bpl + ((size_t)batch * NT) * (N_ / 32) * 512 + (size_t)lane * 8;

  float4 st[4];
#pragma unroll
  for (int i = 0; i < 4; ++i)
    st[i] = *(const float4*)(Ab + (size_t)(srow + 16 * i) * N_ + scol * 4);
#pragma unroll
  for (int i = 0; i < 4; ++i)
    *(float4*)&at[0][srow + 16 * i][scol * 4] = st[i];
  __syncthreads();

  f32x4 acc[NT];
#pragma unroll
  for (int c = 0; c < NT; ++c) acc[c] = (f32x4){0.f, 0.f, 0.f, 0.f};

  for (int t = 0; t < NTILE; ++t) {
    const int kk = t * BK;
    const int buf = t & 1;
    if (t + 1 < NTILE) {                       // issue next-tile loads EARLY
#pragma unroll
      for (int i = 0; i < 4; ++i)
        st[i] = *(const float4*)(Ab + (size_t)(srow + 16 * i) * N_ + (kk + BK) + scol * 4);
      __builtin_amdgcn_sched_barrier(0);       // pin: loads must not sink
    }
#pragma unroll
    for (int c = 0; c < 2; ++c) {              // two 32-K chunks per tile
      const float* ar = &at[buf][wave * 16 + (lane & 15)][c * 32 + (lane >> 4) * 8];
      float4 a0 = *(const float4*)ar;
      float4 a1 = *(const float4*)(ar + 4);
      short8 ahi, alo;
      cvt_split(a0, a1, ahi, alo);
      const size_t co = (cg0 + (kk >> 5) + c) * 512;
#pragma unroll
      for (int ch = 0; ch < NT; ++ch) {
        union { short8 s; uint4 u; } bh, bl;
        bh.u = *(const uint4*)(bhb + ((size_t)ch * (N_ / 32)) * 512 + co);
        bl.u = *(const uint4*)(blb + ((size_t)ch * (N_ / 32)) * 512 + co);
        acc[ch] = __builtin_amdgcn_mfma_f32_16x16x32_bf16(ahi, bh.s, acc[ch], 0, 0, 0);
        acc[ch] = __builtin_amdgcn_mfma_f32_16x16x32_bf16(ahi, bl.s, acc[ch], 0, 0, 0);
        acc[ch] = __builtin_amdgcn_mfma_f32_16x16x32_bf16(alo, bh.s, acc[ch], 0, 0, 0);
      }
    }
    if (t + 1 < NTILE) {                       // write staged regs to other buffer
#pragma unroll
      for (int i = 0; i < 4; ++i)
        *(float4*)&at[buf ^ 1][srow + 16 * i][scol * 4] = st[i];
    }
    __syncthreads();
  }
  // C/D layout (m89): col = lane&15, row = (lane>>4)*4 + j
  const int orow = m0 + wave * 16 + ((lane >> 4) << 2);
  float* pp = P + ((size_t)(z * B_ + batch) * N_ + orow) * H + (lane & 15);
#pragma unroll
  for (int ch = 0; ch < NT; ++ch)
#pragma unroll
    for (int j = 0; j < 4; ++j)
      pp[(size_t)j * H + ch * 16] = acc[ch][j];
}

// -------- fused: h2 = relu(sum_z P2 + b2); dense partials vs Wd --------
__global__ __launch_bounds__(512) void k_densefuse(const float* __restrict__ P2,
                                                   const float* __restrict__ b2,
                                                   const float* __restrict__ Wd,
                                                   float* __restrict__ part) {
  constexpr int KC = 512;                  // 512 flat elems = 8 n-rows x 64 h
  __shared__ float hs[B_][KC];
  __shared__ float psum[B_][D1_];
  const int kc0 = blockIdx.x * KC;
  const int n0 = blockIdx.x * 8;
  const int tid = threadIdx.x;
  constexpr size_t TOT = (size_t)B_ * N_ * H2_;   // one z-slice
#pragma unroll
  for (int i = 0; i < 2; ++i) {            // reduce 4 partials + bias + relu
    int q = tid + i * 512;
    int b = q >> 7, k4 = (q & 127) * 4;
    int nl = k4 >> 6, h = k4 & 63;
    size_t base = (((size_t)b * N_) + n0 + nl) * H2_ + h;
    float4 v0 = *(const float4*)(P2 + base);
    float4 v1 = *(const float4*)(P2 + base + TOT);
    float4 v2 = *(const float4*)(P2 + base + 2 * TOT);
    float4 v3 = *(const float4*)(P2 + base + 3 * TOT);
    float4 bv = *(const float4*)(b2 + h);
    hs[b][k4 + 0] = fmaxf(v0.x + v1.x + v2.x + v3.x + bv.x, 0.f);
    hs[b][k4 + 1] = fmaxf(v0.y + v1.y + v2.y + v3.y + bv.y, 0.f);
    hs[b][k4 + 2] = fmaxf(v0.z + v1.z + v2.z + v3.z + bv.z, 0.f);
    hs[b][k4 + 3] = fmaxf(v0.w + v1.w + v2.w + v3.w + bv.w, 0.f);
  }
  __syncthreads();
  const int d0 = (tid & 31) * 4;           // 4 output cols
  const int b  = (tid >> 5) & 7;           // batch
  const int ks = tid >> 8;                 // in-block k-split (0/1)
  float a0 = 0.f, a1 = 0.f, a2 = 0.f, a3 = 0.f;
  const float* wp = Wd + ((size_t)kc0 + ks * 256) * D1_ + d0;
  const float* hp = &hs[b][ks * 256];
#pragma unroll 4
  for (int k = 0; k < 256; ++k) {
    float4 w = *(const float4*)(wp + (size_t)k * D1_);
    float h = hp[k];
    a0 = fmaf(h, w.x, a0); a1 = fmaf(h, w.y, a1);
    a2 = fmaf(h, w.z, a2); a3 = fmaf(h, w.w, a3);
  }
  if (ks == 1) {
    psum[b][d0] = a0; psum[b][d0 + 1] = a1; psum[b][d0 + 2] = a2; psum[b][d0 + 3] = a3;
  }
  __syncthreads();
  if (ks == 0) {
    float* pp = part + ((size_t)blockIdx.x * B_ + b) * D1_ + d0;
    *(float4*)pp = make_float4(a0 + psum[b][d0], a1 + psum[b][d0 + 1],
                               a2 + psum[b][d0 + 2], a3 + psum[b][d0 + 3]);
  }
}

// -------- fused: reduce dense partials + bias + relu + final sigmoid --------
__global__ __launch_bounds__(1024) void k_dense_final(const float* __restrict__ part,
                                                      const float* __restrict__ bd,
                                                      const float* __restrict__ Wo,
                                                      const float* __restrict__ bo,
                                                      float* __restrict__ out) {
  __shared__ float hd[B_ * D1_];
  const int tid = threadIdx.x;             // 0..1023 = b*128+d
  float s = 0.f;
  for (int i = 0; i < 256; ++i) s += part[(size_t)i * (B_ * D1_) + tid];
  hd[tid] = fmaxf(s + bd[tid & (D1_ - 1)], 0.f);
  __syncthreads();
  if (tid < 512) {
    int w = tid >> 6, l = tid & 63;
    float v = hd[w * D1_ + l] * Wo[l] + hd[w * D1_ + 64 + l] * Wo[64 + l];
#pragma unroll
    for (int off = 32; off; off >>= 1) v += __shfl_down(v, off, 64);
    if (l == 0) out[w] = 1.f / (1.f + expf(-(v + bo[0])));
  }
}

extern "C" void kernel_launch(void* const* d_in, const int* in_sizes, int n_in,
                              void* d_out, int out_size, void* d_ws, size_t ws_size,
                              hipStream_t stream) {
  const float* x  = (const float*)d_in[0];
  const float* a  = (const float*)d_in[1];
  const float* W1 = (const float*)d_in[2];
  const float* b1 = (const float*)d_in[3];
  const float* W2 = (const float*)d_in[4];
  const float* b2 = (const float*)d_in[5];
  const float* Wd = (const float*)d_in[6];
  const float* bd = (const float*)d_in[7];
  const float* Wo = (const float*)d_in[8];
  const float* bo = (const float*)d_in[9];
  float* out = (float*)d_out;

  // workspace (floats), lifetime-aliased; total 6,029,312 floats = 24.1 MB:
  //  [0, 4194304)          P: agemm partials (H1 uses first 2M, H2 all 4M)
  //  [4194304, 4456448)    Bt1h   [4456448, 4718592) Bt1l
  //  [4718592, 5242880)    Bt2h   [5242880, 5767168) Bt2l
  //  [5767168, 6029312)    dpart (256*8*128)
  float* ws    = (float*)d_ws;
  float* P     = ws;
  u16*   Bt1h  = (u16*)(ws + 4194304);
  u16*   Bt1l  = (u16*)(ws + 4456448);
  u16*   Bt2h  = (u16*)(ws + 4718592);
  u16*   Bt2l  = (u16*)(ws + 5242880);
  float* dpart = ws + 5767168;

  k_xw1cvt<<<dim3(N_ / 64, B_), 256, 0, stream>>>(x, W1, Bt1h, Bt1l);
  k_agemm_mfma<H1_><<<dim3(N_ / 64, B_, KS_), 256, 0, stream>>>(a, Bt1h, Bt1l, P);
  k_l1fuse<<<dim3(N_ / 64, B_), 256, 0, stream>>>(P, b1, W2, Bt2h, Bt2l);
  k_agemm_mfma<H2_><<<dim3(N_ / 64, B_, KS_), 256, 0, stream>>>(a, Bt2h, Bt2l, P);
  k_densefuse<<<(N_ * H2_) / 512, 512, 0, stream>>>(P, b2, Wd, dpart);
  k_dense_final<<<1, 1024, 0, stream>>>(dpart, bd, Wo, bo, out);
}

// Round 10
// 113.628 us; speedup vs baseline: 2.1586x; 1.0368x over previous
//
#include <hip/hip_runtime.h>
#include <math.h>

#define B_  8
#define N_  2048
#define F_  128
#define H1_ 32
#define H2_ 64
#define D1_ 128
#define KS_ 8            // K-split factor for the A-GEMMs
#define KSEG_ (N_ / KS_) // 256 K per block

typedef unsigned short u16;
typedef unsigned int   u32;
typedef __attribute__((ext_vector_type(8))) short short8;  // 8 bf16 (4 VGPRs)
typedef __attribute__((ext_vector_type(4))) float f32x4;

// ---- round-to-nearest-even fp32 -> bf16, two at a time, packed into u32 ----
__device__ __forceinline__ u32 rne2(float e0, float e1) {
  u32 u0 = __float_as_uint(e0), u1 = __float_as_uint(e1);
  u0 = (u0 + 0x7FFFu + ((u0 >> 16) & 1u)) >> 16;
  u1 = (u1 + 0x7FFFu + ((u1 >> 16) & 1u)) & 0xFFFF0000u;
  return u0 | u1;
}
__device__ __forceinline__ uint4 rne8(const float4 a, const float4 b) {
  return make_uint4(rne2(a.x, a.y), rne2(a.z, a.w), rne2(b.x, b.y), rne2(b.z, b.w));
}

// ---- pack a [64][LDST] fp32 LDS tile (rows = n, cols = h) into MFMA B-frag
// order (bf16 RNE). frag (b, ch, cg): 64 lanes x 8 bf16,
// lane = slot*16+cl holds B[k=cg*32+slot*8+i][col].
template<int H, int LDST>
__device__ __forceinline__ void pack_frags(const float* s, int b, int cgbase,
                                           u16* __restrict__ oh, int tid) {
  constexpr int CGRP = H / 16;
  constexpr int PASSES = H * 8 / 256;
#pragma unroll
  for (int p = 0; p < PASSES; ++p) {
    int q = tid + p * 256;
    int h = q >> 3, nn = (q & 7) * 8;           // 8 consecutive n for col h
    u32 hw[4];
#pragma unroll
    for (int j = 0; j < 4; ++j)
      hw[j] = rne2(s[(nn + 2 * j) * LDST + h], s[(nn + 2 * j + 1) * LDST + h]);
    int ch = h >> 4, cl = h & 15;
    int cg = cgbase + (nn >> 5);
    int lanep = ((nn >> 3) & 3) * 16 + cl;
    size_t o = ((((size_t)b * CGRP + ch) * (N_ / 32) + cg) * 64 + lanep) * 8;
    *(uint4*)(oh + o) = make_uint4(hw[0], hw[1], hw[2], hw[3]);
  }
}

// -------- fused: xw1 = x @ W1 (64-row tile), then pack (bf16) for agemm --------
__global__ __launch_bounds__(256) void k_xw1cvt(const float* __restrict__ x,
                                                const float* __restrict__ W1,
                                                u16* __restrict__ oh) {
  __shared__ float xs[64][F_];        // 32 KB
  __shared__ float w1s[F_ * H1_];     // 16 KB
  __shared__ float s[64][H1_ + 1];    // 8.4 KB
  const int b = blockIdx.y;
  const int n0 = blockIdx.x * 64;
  const int tid = threadIdx.x;
  const float* xp = x + ((size_t)b * N_ + n0) * F_;
#pragma unroll
  for (int i = 0; i < 8; ++i) {       // stage x tile: 8192 floats
    int q = tid + i * 256;
    int r = q >> 5, c4 = (q & 31) * 4;
    *(float4*)&xs[r][c4] = *(const float4*)(xp + (size_t)r * F_ + c4);
  }
#pragma unroll
  for (int i = 0; i < 4; ++i)         // stage W1: 4096 floats
    ((float4*)w1s)[tid + i * 256] = ((const float4*)W1)[tid + i * 256];
  __syncthreads();
  const int r = tid >> 2, c0 = (tid & 3) * 8;
  float acc[8] = {};
#pragma unroll
  for (int k = 0; k < F_; ++k) {
    float xv = xs[r][k];
#pragma unroll
    for (int j = 0; j < 8; ++j)
      acc[j] = fmaf(xv, w1s[k * H1_ + c0 + j], acc[j]);
  }
#pragma unroll
  for (int j = 0; j < 8; ++j) s[r][c0 + j] = acc[j];
  __syncthreads();
  pack_frags<H1_, H1_ + 1>(&s[0][0], b, blockIdx.x * 2, oh, tid);
}

// -------- fused: h1 = relu(sum_z P1 + b1); hw2 = h1 @ W2; pack (bf16) --------
__global__ __launch_bounds__(256) void k_l1fuse(const float* __restrict__ P1,
                                                const float* __restrict__ b1,
                                                const float* __restrict__ W2,
                                                u16* __restrict__ oh) {
  __shared__ float h1s[64][H1_ + 1];   // 8.4 KB
  __shared__ float w2s[H1_ * H2_];     // 8 KB
  __shared__ float hw2s[64][H2_ + 1];  // 16.6 KB
  const int b = blockIdx.y;
  const int n0 = blockIdx.x * 64;
  const int tid = threadIdx.x;
  constexpr size_t TOT = (size_t)B_ * N_ * H1_;   // one z-slice
#pragma unroll
  for (int i = 0; i < 2; ++i) {        // reduce KS partials + bias + relu
    int q = tid + i * 256;
    int r = q >> 3, h4 = (q & 7) * 4;
    size_t base = (((size_t)b * N_) + n0 + r) * H1_ + h4;
    float4 bv = *(const float4*)(b1 + h4);
    float a0 = bv.x, a1 = bv.y, a2 = bv.z, a3 = bv.w;
#pragma unroll
    for (int zz = 0; zz < KS_; ++zz) {
      float4 v = *(const float4*)(P1 + base + (size_t)zz * TOT);
      a0 += v.x; a1 += v.y; a2 += v.z; a3 += v.w;
    }
    h1s[r][h4 + 0] = fmaxf(a0, 0.f);
    h1s[r][h4 + 1] = fmaxf(a1, 0.f);
    h1s[r][h4 + 2] = fmaxf(a2, 0.f);
    h1s[r][h4 + 3] = fmaxf(a3, 0.f);
  }
#pragma unroll
  for (int i = 0; i < 2; ++i)          // stage W2: 2048 floats
    ((float4*)w2s)[tid + i * 256] = ((const float4*)W2)[tid + i * 256];
  __syncthreads();
  const int r = tid >> 2, c0 = (tid & 3) * 16;
  float acc[16] = {};
#pragma unroll
  for (int k = 0; k < H1_; ++k) {
    float hv = h1s[r][k];
#pragma unroll
    for (int j = 0; j < 16; ++j)
      acc[j] = fmaf(hv, w2s[k * H2_ + c0 + j], acc[j]);
  }
#pragma unroll
  for (int j = 0; j < 16; ++j) hw2s[r][c0 + j] = acc[j];
  __syncthreads();
  pack_frags<H2_, H2_ + 1>(&hw2s[0][0], b, blockIdx.x * 2, oh, tid);
}

// -------- MFMA A-GEMM partials: plain bf16 (RNE), A staged as bf16 in LDS --------
// Grid (N/64, B, KS=8) = 2048 blocks, 4 waves. LDS tile [2][64][72] u16 = 18.4 KB
// (dbuf) -> 6 blocks/CU at (256,6) = 24 waves/CU. Per 32-K chunk per 16-col
// group: 1 ds_read_b128 (shared across groups) + 1 B uint4 + 1 MFMA.
// Staging: thread = quarter-row (16 fp32 -> RNE bf16 -> 2 ds_write_b128);
// next-tile loads issued before compute, pinned by sched_barrier.
template<int H>
__global__ __launch_bounds__(256, 6) void k_agemm_mfma(const float* __restrict__ A,
                                                       const u16* __restrict__ Bph,
                                                       float* __restrict__ P) {
  constexpr int NT = H / 16;
  constexpr int BK = 64;
  constexpr int NTILE = KSEG_ / BK;            // 4
  __shared__ u16 at[2][64][72];

  const int batch = blockIdx.y;
  const int z = blockIdx.z;
  const int m0 = blockIdx.x * 64;
  const int tid = threadIdx.x;
  const int lane = tid & 63;
  const int wave = tid >> 6;

  const float* Ab = A + (size_t)batch * N_ * N_ + (size_t)m0 * N_ + (size_t)z * KSEG_;
  const int srow = tid >> 2, sc0 = (tid & 3) * 16;  // staging: quarter-row each

  const size_t cg0 = (size_t)z * (KSEG_ / 32); // first 32-chunk of this K segment
  const u16* bhb = Bph + ((size_t)batch * NT) * (N_ / 32) * 512 + (size_t)lane * 8;

  float4 st[4];
#pragma unroll
  for (int i = 0; i < 4; ++i)
    st[i] = *(const float4*)(Ab + (size_t)srow * N_ + sc0 + 4 * i);
  *(uint4*)&at[0][srow][sc0]     = rne8(st[0], st[1]);
  *(uint4*)&at[0][srow][sc0 + 8] = rne8(st[2], st[3]);
  __syncthreads();

  f32x4 acc[NT];
#pragma unroll
  for (int c = 0; c < NT; ++c) acc[c] = (f32x4){0.f, 0.f, 0.f, 0.f};

  for (int t = 0; t < NTILE; ++t) {
    const int kk = t * BK;
    const int buf = t & 1;
    if (t + 1 < NTILE) {                       // issue next-tile loads EARLY
#pragma unroll
      for (int i = 0; i < 4; ++i)
        st[i] = *(const float4*)(Ab + (size_t)srow * N_ + (kk + BK) + sc0 + 4 * i);
      __builtin_amdgcn_sched_barrier(0);       // pin: loads must not sink
    }
#pragma unroll
    for (int c = 0; c < 2; ++c) {              // two 32-K chunks per tile
      short8 av = *(const short8*)&at[buf][wave * 16 + (lane & 15)][c * 32 + (lane >> 4) * 8];
      const size_t co = (cg0 + (kk >> 5) + c) * 512;
#pragma unroll
      for (int ch = 0; ch < NT; ++ch) {
        union { short8 s; uint4 u; } bh;
        bh.u = *(const uint4*)(bhb + ((size_t)ch * (N_ / 32)) * 512 + co);
        acc[ch] = __builtin_amdgcn_mfma_f32_16x16x32_bf16(av, bh.s, acc[ch], 0, 0, 0);
      }
    }
    if (t + 1 < NTILE) {                       // cvt + write staged regs to other buffer
      *(uint4*)&at[buf ^ 1][srow][sc0]     = rne8(st[0], st[1]);
      *(uint4*)&at[buf ^ 1][srow][sc0 + 8] = rne8(st[2], st[3]);
    }
    __syncthreads();
  }
  // C/D layout (m89): col = lane&15, row = (lane>>4)*4 + j
  const int orow = m0 + wave * 16 + ((lane >> 4) << 2);
  float* pp = P + ((size_t)(z * B_ + batch) * N_ + orow) * H + (lane & 15);
#pragma unroll
  for (int ch = 0; ch < NT; ++ch)
#pragma unroll
    for (int j = 0; j < 4; ++j)
      pp[(size_t)j * H + ch * 16] = acc[ch][j];
}

// -------- fused: h2 = relu(sum_z P2 + b2); dense partials vs Wd --------
__global__ __launch_bounds__(512) void k_densefuse(const float* __restrict__ P2,
                                                   const float* __restrict__ b2,
                                                   const float* __restrict__ Wd,
                                                   float* __restrict__ part) {
  constexpr int KC = 512;                  // 512 flat elems = 8 n-rows x 64 h
  __shared__ float hs[B_][KC];
  __shared__ float psum[B_][D1_];
  const int kc0 = blockIdx.x * KC;
  const int n0 = blockIdx.x * 8;
  const int tid = threadIdx.x;
  constexpr size_t TOT = (size_t)B_ * N_ * H2_;   // one z-slice
#pragma unroll
  for (int i = 0; i < 2; ++i) {            // reduce KS partials + bias + relu
    int q = tid + i * 512;
    int b = q >> 7, k4 = (q & 127) * 4;
    int nl = k4 >> 6, h = k4 & 63;
    size_t base = (((size_t)b * N_) + n0 + nl) * H2_ + h;
    float4 bv = *(const float4*)(b2 + h);
    float a0 = bv.x, a1 = bv.y, a2 = bv.z, a3 = bv.w;
#pragma unroll
    for (int zz = 0; zz < KS_; ++zz) {
      float4 v = *(const float4*)(P2 + base + (size_t)zz * TOT);
      a0 += v.x; a1 += v.y; a2 += v.z; a3 += v.w;
    }
    hs[b][k4 + 0] = fmaxf(a0, 0.f);
    hs[b][k4 + 1] = fmaxf(a1, 0.f);
    hs[b][k4 + 2] = fmaxf(a2, 0.f);
    hs[b][k4 + 3] = fmaxf(a3, 0.f);
  }
  __syncthreads();
  const int d0 = (tid & 31) * 4;           // 4 output cols
  const int b  = (tid >> 5) & 7;           // batch
  const int ks = tid >> 8;                 // in-block k-split (0/1)
  float a0 = 0.f, a1 = 0.f, a2 = 0.f, a3 = 0.f;
  const float* wp = Wd + ((size_t)kc0 + ks * 256) * D1_ + d0;
  const float* hp = &hs[b][ks * 256];
#pragma unroll 4
  for (int k = 0; k < 256; ++k) {
    float4 w = *(const float4*)(wp + (size_t)k * D1_);
    float h = hp[k];
    a0 = fmaf(h, w.x, a0); a1 = fmaf(h, w.y, a1);
    a2 = fmaf(h, w.z, a2); a3 = fmaf(h, w.w, a3);
  }
  if (ks == 1) {
    psum[b][d0] = a0; psum[b][d0 + 1] = a1; psum[b][d0 + 2] = a2; psum[b][d0 + 3] = a3;
  }
  __syncthreads();
  if (ks == 0) {
    float* pp = part + ((size_t)blockIdx.x * B_ + b) * D1_ + d0;
    *(float4*)pp = make_float4(a0 + psum[b][d0], a1 + psum[b][d0 + 1],
                               a2 + psum[b][d0 + 2], a3 + psum[b][d0 + 3]);
  }
}

// -------- fused: reduce dense partials + bias + relu + final sigmoid --------
__global__ __launch_bounds__(1024) void k_dense_final(const float* __restrict__ part,
                                                      const float* __restrict__ bd,
                                                      const float* __restrict__ Wo,
                                                      const float* __restrict__ bo,
                                                      float* __restrict__ out) {
  __shared__ float hd[B_ * D1_];
  const int tid = threadIdx.x;             // 0..1023 = b*128+d
  float s = 0.f;
  for (int i = 0; i < 256; ++i) s += part[(size_t)i * (B_ * D1_) + tid];
  hd[tid] = fmaxf(s + bd[tid & (D1_ - 1)], 0.f);
  __syncthreads();
  if (tid < 512) {
    int w = tid >> 6, l = tid & 63;
    float v = hd[w * D1_ + l] * Wo[l] + hd[w * D1_ + 64 + l] * Wo[64 + l];
#pragma unroll
    for (int off = 32; off; off >>= 1) v += __shfl_down(v, off, 64);
    if (l == 0) out[w] = 1.f / (1.f + expf(-(v + bo[0])));
  }
}

extern "C" void kernel_launch(void* const* d_in, const int* in_sizes, int n_in,
                              void* d_out, int out_size, void* d_ws, size_t ws_size,
                              hipStream_t stream) {
  const float* x  = (const float*)d_in[0];
  const float* a  = (const float*)d_in[1];
  const float* W1 = (const float*)d_in[2];
  const float* b1 = (const float*)d_in[3];
  const float* W2 = (const float*)d_in[4];
  const float* b2 = (const float*)d_in[5];
  const float* Wd = (const float*)d_in[6];
  const float* bd = (const float*)d_in[7];
  const float* Wo = (const float*)d_in[8];
  const float* bo = (const float*)d_in[9];
  float* out = (float*)d_out;

  // workspace (floats): total 9,437,184 floats = 37.7 MB
  //  [0, 8388608)          P: agemm partials (H1 uses first 4M, H2 all 8M)
  //  [8388608, 8650752)    Bt1h (bf16, 512K u16)
  //  [8650752, 9175040)    Bt2h (bf16, 1M u16)
  //  [9175040, 9437184)    dpart (256*8*128)
  float* ws    = (float*)d_ws;
  float* P     = ws;
  u16*   Bt1h  = (u16*)(ws + 8388608);
  u16*   Bt2h  = (u16*)(ws + 8650752);
  float* dpart = ws + 9175040;

  k_xw1cvt<<<dim3(N_ / 64, B_), 256, 0, stream>>>(x, W1, Bt1h);
  k_agemm_mfma<H1_><<<dim3(N_ / 64, B_, KS_), 256, 0, stream>>>(a, Bt1h, P);
  k_l1fuse<<<dim3(N_ / 64, B_), 256, 0, stream>>>(P, b1, W2, Bt2h);
  k_agemm_mfma<H2_><<<dim3(N_ / 64, B_, KS_), 256, 0, stream>>>(a, Bt2h, P);
  k_densefuse<<<(N_ * H2_) / 512, 512, 0, stream>>>(P, b2, Wd, dpart);
  k_dense_final<<<1, 1024, 0, stream>>>(dpart, bd, Wo, bo, out);
}

// Round 11
// 103.582 us; speedup vs baseline: 2.3679x; 1.0970x over previous
//
#include <hip/hip_runtime.h>
#include <math.h>

#define B_  8
#define N_  2048
#define F_  128
#define H1_ 32
#define H2_ 64
#define D1_ 128
#define KS_ 4            // K-split factor for the A-GEMMs
#define KSEG_ (N_ / KS_) // 512 K per block

typedef unsigned short u16;
typedef unsigned int   u32;
typedef __attribute__((ext_vector_type(8))) short short8;  // 8 bf16 (4 VGPRs)
typedef __attribute__((ext_vector_type(4))) float f32x4;

// ---- round-to-nearest-even fp32 -> bf16, two at a time, packed into u32 ----
__device__ __forceinline__ u32 rne2(float e0, float e1) {
  u32 u0 = __float_as_uint(e0), u1 = __float_as_uint(e1);
  u0 = (u0 + 0x7FFFu + ((u0 >> 16) & 1u)) >> 16;
  u1 = (u1 + 0x7FFFu + ((u1 >> 16) & 1u)) & 0xFFFF0000u;
  return u0 | u1;
}
__device__ __forceinline__ uint4 rne8(const float4 a, const float4 b) {
  return make_uint4(rne2(a.x, a.y), rne2(a.z, a.w), rne2(b.x, b.y), rne2(b.z, b.w));
}

// ---- pack a [64][LDST] fp32 LDS tile (rows = n, cols = h) into MFMA B-frag
// order (bf16 RNE). frag (b, ch, cg): 64 lanes x 8 bf16,
// lane = slot*16+cl holds B[k=cg*32+slot*8+i][col].
template<int H, int LDST>
__device__ __forceinline__ void pack_frags(const float* s, int b, int cgbase,
                                           u16* __restrict__ oh, int tid) {
  constexpr int CGRP = H / 16;
  constexpr int PASSES = H * 8 / 256;
#pragma unroll
  for (int p = 0; p < PASSES; ++p) {
    int q = tid + p * 256;
    int h = q >> 3, nn = (q & 7) * 8;           // 8 consecutive n for col h
    u32 hw[4];
#pragma unroll
    for (int j = 0; j < 4; ++j)
      hw[j] = rne2(s[(nn + 2 * j) * LDST + h], s[(nn + 2 * j + 1) * LDST + h]);
    int ch = h >> 4, cl = h & 15;
    int cg = cgbase + (nn >> 5);
    int lanep = ((nn >> 3) & 3) * 16 + cl;
    size_t o = ((((size_t)b * CGRP + ch) * (N_ / 32) + cg) * 64 + lanep) * 8;
    *(uint4*)(oh + o) = make_uint4(hw[0], hw[1], hw[2], hw[3]);
  }
}

// -------- fused: xw1 = x @ W1 (64-row tile), then pack (bf16) for agemm --------
__global__ __launch_bounds__(256) void k_xw1cvt(const float* __restrict__ x,
                                                const float* __restrict__ W1,
                                                u16* __restrict__ oh) {
  __shared__ float xs[64][F_];        // 32 KB
  __shared__ float w1s[F_ * H1_];     // 16 KB
  __shared__ float s[64][H1_ + 1];    // 8.4 KB
  const int b = blockIdx.y;
  const int n0 = blockIdx.x * 64;
  const int tid = threadIdx.x;
  const float* xp = x + ((size_t)b * N_ + n0) * F_;
#pragma unroll
  for (int i = 0; i < 8; ++i) {       // stage x tile: 8192 floats
    int q = tid + i * 256;
    int r = q >> 5, c4 = (q & 31) * 4;
    *(float4*)&xs[r][c4] = *(const float4*)(xp + (size_t)r * F_ + c4);
  }
#pragma unroll
  for (int i = 0; i < 4; ++i)         // stage W1: 4096 floats
    ((float4*)w1s)[tid + i * 256] = ((const float4*)W1)[tid + i * 256];
  __syncthreads();
  const int r = tid >> 2, c0 = (tid & 3) * 8;
  float acc[8] = {};
#pragma unroll
  for (int k = 0; k < F_; ++k) {
    float xv = xs[r][k];
#pragma unroll
    for (int j = 0; j < 8; ++j)
      acc[j] = fmaf(xv, w1s[k * H1_ + c0 + j], acc[j]);
  }
#pragma unroll
  for (int j = 0; j < 8; ++j) s[r][c0 + j] = acc[j];
  __syncthreads();
  pack_frags<H1_, H1_ + 1>(&s[0][0], b, blockIdx.x * 2, oh, tid);
}

// -------- fused: h1 = relu(sum_z P1 + b1); hw2 = h1 @ W2; pack (bf16) --------
__global__ __launch_bounds__(256) void k_l1fuse(const float* __restrict__ P1,
                                                const float* __restrict__ b1,
                                                const float* __restrict__ W2,
                                                u16* __restrict__ oh) {
  __shared__ float h1s[64][H1_ + 1];   // 8.4 KB
  __shared__ float w2s[H1_ * H2_];     // 8 KB
  __shared__ float hw2s[64][H2_ + 1];  // 16.6 KB
  const int b = blockIdx.y;
  const int n0 = blockIdx.x * 64;
  const int tid = threadIdx.x;
  constexpr size_t TOT = (size_t)B_ * N_ * H1_;   // one z-slice
#pragma unroll
  for (int i = 0; i < 2; ++i) {        // reduce KS partials + bias + relu
    int q = tid + i * 256;
    int r = q >> 3, h4 = (q & 7) * 4;
    size_t base = (((size_t)b * N_) + n0 + r) * H1_ + h4;
    float4 bv = *(const float4*)(b1 + h4);
    float a0 = bv.x, a1 = bv.y, a2 = bv.z, a3 = bv.w;
#pragma unroll
    for (int zz = 0; zz < KS_; ++zz) {
      float4 v = *(const float4*)(P1 + base + (size_t)zz * TOT);
      a0 += v.x; a1 += v.y; a2 += v.z; a3 += v.w;
    }
    h1s[r][h4 + 0] = fmaxf(a0, 0.f);
    h1s[r][h4 + 1] = fmaxf(a1, 0.f);
    h1s[r][h4 + 2] = fmaxf(a2, 0.f);
    h1s[r][h4 + 3] = fmaxf(a3, 0.f);
  }
#pragma unroll
  for (int i = 0; i < 2; ++i)          // stage W2: 2048 floats
    ((float4*)w2s)[tid + i * 256] = ((const float4*)W2)[tid + i * 256];
  __syncthreads();
  const int r = tid >> 2, c0 = (tid & 3) * 16;
  float acc[16] = {};
#pragma unroll
  for (int k = 0; k < H1_; ++k) {
    float hv = h1s[r][k];
#pragma unroll
    for (int j = 0; j < 16; ++j)
      acc[j] = fmaf(hv, w2s[k * H2_ + c0 + j], acc[j]);
  }
#pragma unroll
  for (int j = 0; j < 16; ++j) hw2s[r][c0 + j] = acc[j];
  __syncthreads();
  pack_frags<H2_, H2_ + 1>(&hw2s[0][0], b, blockIdx.x * 2, oh, tid);
}

// -------- MFMA A-GEMM partials: bf16, BOTH A and B staged through LDS --------
// Grid (N/64, B, KS=4) = 1024 blocks (exactly 4/CU co-resident, 16 waves/CU).
// Per iteration: issue A-tile (4 float4) + B-tile (BL uint4) global loads at
// the TOP (sched_barrier pins them); compute phase reads ONLY LDS (no vmcnt
// waits -> A prefetch is never drained by B loads, unlike r8-r10); single
// vmcnt wait at the ds_write, one full compute-phase after issue.
template<int H>
__global__ __launch_bounds__(256, 4) void k_agemm_mfma(const float* __restrict__ A,
                                                       const u16* __restrict__ Bph,
                                                       float* __restrict__ P) {
  constexpr int NT = H / 16;
  constexpr int BK = 64;
  constexpr int NTILE = KSEG_ / BK;            // 8
  constexpr int CHSTR = (N_ / 32) * 512;       // u16 stride between colgroups
  constexpr int BL = NT / 2;                   // B uint4 loads per thread per tile
  __shared__ u16 at[2][64][72];                // A tile bf16 (dbuf), 18.4 KB
  __shared__ u16 bt[2][2][NT][64][8];          // B frags (dbuf): H2 16 KB, H1 8 KB

  const int batch = blockIdx.y;
  const int z = blockIdx.z;
  const int m0 = blockIdx.x * 64;
  const int tid = threadIdx.x;
  const int lane = tid & 63;
  const int wave = tid >> 6;

  const float* Ab = A + (size_t)batch * N_ * N_ + (size_t)m0 * N_ + (size_t)z * KSEG_;
  const int srow = tid >> 2, sc0 = (tid & 3) * 16;  // A staging: quarter-row each

  const int cg0 = z * (KSEG_ / 32);            // first 32-chunk of this K segment
  const u16* Bb = Bph + (size_t)batch * NT * CHSTR;

  float4 sa[4];
  uint4  sb[BL];

  // ---- prologue: tile 0 ----
#pragma unroll
  for (int i = 0; i < 4; ++i)
    sa[i] = *(const float4*)(Ab + (size_t)srow * N_ + sc0 + 4 * i);
#pragma unroll
  for (int i = 0; i < BL; ++i) {
    int q = tid + i * 256, seg = q >> 6, l2 = q & 63;
    int cc = seg / NT, ch = seg % NT;
    sb[i] = *(const uint4*)(Bb + (size_t)ch * CHSTR + (size_t)(cg0 + cc) * 512 + l2 * 8);
  }
  *(uint4*)&at[0][srow][sc0]     = rne8(sa[0], sa[1]);
  *(uint4*)&at[0][srow][sc0 + 8] = rne8(sa[2], sa[3]);
#pragma unroll
  for (int i = 0; i < BL; ++i) {
    int q = tid + i * 256, seg = q >> 6, l2 = q & 63;
    int cc = seg / NT, ch = seg % NT;
    *(uint4*)&bt[0][cc][ch][l2][0] = sb[i];
  }
  __syncthreads();

  f32x4 acc[NT];
#pragma unroll
  for (int c = 0; c < NT; ++c) acc[c] = (f32x4){0.f, 0.f, 0.f, 0.f};

  for (int t = 0; t < NTILE; ++t) {
    const int buf = t & 1;
    if (t + 1 < NTILE) {                       // issue next-tile A+B loads EARLY
      const int kk1 = (t + 1) * BK;
#pragma unroll
      for (int i = 0; i < 4; ++i)
        sa[i] = *(const float4*)(Ab + (size_t)srow * N_ + kk1 + sc0 + 4 * i);
#pragma unroll
      for (int i = 0; i < BL; ++i) {
        int q = tid + i * 256, seg = q >> 6, l2 = q & 63;
        int cc = seg / NT, ch = seg % NT;
        sb[i] = *(const uint4*)(Bb + (size_t)ch * CHSTR
                                + (size_t)(cg0 + 2 * (t + 1) + cc) * 512 + l2 * 8);
      }
      __builtin_amdgcn_sched_barrier(0);       // pin: loads must not sink
    }
#pragma unroll
    for (int c = 0; c < 2; ++c) {              // two 32-K chunks per tile, LDS-only
      short8 av = *(const short8*)&at[buf][wave * 16 + (lane & 15)][c * 32 + (lane >> 4) * 8];
#pragma unroll
      for (int ch = 0; ch < NT; ++ch) {
        short8 bv = *(const short8*)&bt[buf][c][ch][lane][0];
        acc[ch] = __builtin_amdgcn_mfma_f32_16x16x32_bf16(av, bv, acc[ch], 0, 0, 0);
      }
    }
    if (t + 1 < NTILE) {                       // cvt + write staged regs (one vmcnt wait)
      *(uint4*)&at[buf ^ 1][srow][sc0]     = rne8(sa[0], sa[1]);
      *(uint4*)&at[buf ^ 1][srow][sc0 + 8] = rne8(sa[2], sa[3]);
#pragma unroll
      for (int i = 0; i < BL; ++i) {
        int q = tid + i * 256, seg = q >> 6, l2 = q & 63;
        int cc = seg / NT, ch = seg % NT;
        *(uint4*)&bt[buf ^ 1][cc][ch][l2][0] = sb[i];
      }
    }
    __syncthreads();
  }
  // C/D layout (m89): col = lane&15, row = (lane>>4)*4 + j
  const int orow = m0 + wave * 16 + ((lane >> 4) << 2);
  float* pp = P + ((size_t)(z * B_ + batch) * N_ + orow) * H + (lane & 15);
#pragma unroll
  for (int ch = 0; ch < NT; ++ch)
#pragma unroll
    for (int j = 0; j < 4; ++j)
      pp[(size_t)j * H + ch * 16] = acc[ch][j];
}

// -------- fused: h2 = relu(sum_z P2 + b2); dense partials vs Wd --------
__global__ __launch_bounds__(512) void k_densefuse(const float* __restrict__ P2,
                                                   const float* __restrict__ b2,
                                                   const float* __restrict__ Wd,
                                                   float* __restrict__ part) {
  constexpr int KC = 512;                  // 512 flat elems = 8 n-rows x 64 h
  __shared__ float hs[B_][KC];
  __shared__ float psum[B_][D1_];
  const int kc0 = blockIdx.x * KC;
  const int n0 = blockIdx.x * 8;
  const int tid = threadIdx.x;
  constexpr size_t TOT = (size_t)B_ * N_ * H2_;   // one z-slice
#pragma unroll
  for (int i = 0; i < 2; ++i) {            // reduce KS partials + bias + relu
    int q = tid + i * 512;
    int b = q >> 7, k4 = (q & 127) * 4;
    int nl = k4 >> 6, h = k4 & 63;
    size_t base = (((size_t)b * N_) + n0 + nl) * H2_ + h;
    float4 bv = *(const float4*)(b2 + h);
    float a0 = bv.x, a1 = bv.y, a2 = bv.z, a3 = bv.w;
#pragma unroll
    for (int zz = 0; zz < KS_; ++zz) {
      float4 v = *(const float4*)(P2 + base + (size_t)zz * TOT);
      a0 += v.x; a1 += v.y; a2 += v.z; a3 += v.w;
    }
    hs[b][k4 + 0] = fmaxf(a0, 0.f);
    hs[b][k4 + 1] = fmaxf(a1, 0.f);
    hs[b][k4 + 2] = fmaxf(a2, 0.f);
    hs[b][k4 + 3] = fmaxf(a3, 0.f);
  }
  __syncthreads();
  const int d0 = (tid & 31) * 4;           // 4 output cols
  const int b  = (tid >> 5) & 7;           // batch
  const int ks = tid >> 8;                 // in-block k-split (0/1)
  float a0 = 0.f, a1 = 0.f, a2 = 0.f, a3 = 0.f;
  const float* wp = Wd + ((size_t)kc0 + ks * 256) * D1_ + d0;
  const float* hp = &hs[b][ks * 256];
#pragma unroll 4
  for (int k = 0; k < 256; ++k) {
    float4 w = *(const float4*)(wp + (size_t)k * D1_);
    float h = hp[k];
    a0 = fmaf(h, w.x, a0); a1 = fmaf(h, w.y, a1);
    a2 = fmaf(h, w.z, a2); a3 = fmaf(h, w.w, a3);
  }
  if (ks == 1) {
    psum[b][d0] = a0; psum[b][d0 + 1] = a1; psum[b][d0 + 2] = a2; psum[b][d0 + 3] = a3;
  }
  __syncthreads();
  if (ks == 0) {
    float* pp = part + ((size_t)blockIdx.x * B_ + b) * D1_ + d0;
    *(float4*)pp = make_float4(a0 + psum[b][d0], a1 + psum[b][d0 + 1],
                               a2 + psum[b][d0 + 2], a3 + psum[b][d0 + 3]);
  }
}

// -------- fused: reduce dense partials + bias + relu + final sigmoid --------
__global__ __launch_bounds__(1024) void k_dense_final(const float* __restrict__ part,
                                                      const float* __restrict__ bd,
                                                      const float* __restrict__ Wo,
                                                      const float* __restrict__ bo,
                                                      float* __restrict__ out) {
  __shared__ float hd[B_ * D1_];
  const int tid = threadIdx.x;             // 0..1023 = b*128+d
  float s = 0.f;
  for (int i = 0; i < 256; ++i) s += part[(size_t)i * (B_ * D1_) + tid];
  hd[tid] = fmaxf(s + bd[tid & (D1_ - 1)], 0.f);
  __syncthreads();
  if (tid < 512) {
    int w = tid >> 6, l = tid & 63;
    float v = hd[w * D1_ + l] * Wo[l] + hd[w * D1_ + 64 + l] * Wo[64 + l];
#pragma unroll
    for (int off = 32; off; off >>= 1) v += __shfl_down(v, off, 64);
    if (l == 0) out[w] = 1.f / (1.f + expf(-(v + bo[0])));
  }
}

extern "C" void kernel_launch(void* const* d_in, const int* in_sizes, int n_in,
                              void* d_out, int out_size, void* d_ws, size_t ws_size,
                              hipStream_t stream) {
  const float* x  = (const float*)d_in[0];
  const float* a  = (const float*)d_in[1];
  const float* W1 = (const float*)d_in[2];
  const float* b1 = (const float*)d_in[3];
  const float* W2 = (const float*)d_in[4];
  const float* b2 = (const float*)d_in[5];
  const float* Wd = (const float*)d_in[6];
  const float* bd = (const float*)d_in[7];
  const float* Wo = (const float*)d_in[8];
  const float* bo = (const float*)d_in[9];
  float* out = (float*)d_out;

  // workspace (floats): total 5,242,880 floats = 21 MB
  //  [0, 4194304)          P: agemm partials KS=4 (H1 uses first 2M, H2 all 4M)
  //  [4194304, 4456448)    Bt1h (bf16, 512K u16)
  //  [4456448, 4980736)    Bt2h (bf16, 1M u16)
  //  [4980736, 5242880)    dpart (256*8*128)
  float* ws    = (float*)d_ws;
  float* P     = ws;
  u16*   Bt1h  = (u16*)(ws + 4194304);
  u16*   Bt2h  = (u16*)(ws + 4456448);
  float* dpart = ws + 4980736;

  k_xw1cvt<<<dim3(N_ / 64, B_), 256, 0, stream>>>(x, W1, Bt1h);
  k_agemm_mfma<H1_><<<dim3(N_ / 64, B_, KS_), 256, 0, stream>>>(a, Bt1h, P);
  k_l1fuse<<<dim3(N_ / 64, B_), 256, 0, stream>>>(P, b1, W2, Bt2h);
  k_agemm_mfma<H2_><<<dim3(N_ / 64, B_, KS_), 256, 0, stream>>>(a, Bt2h, P);
  k_densefuse<<<(N_ * H2_) / 512, 512, 0, stream>>>(P, b2, Wd, dpart);
  k_dense_final<<<1, 1024, 0, stream>>>(dpart, bd, Wo, bo, out);
}